// Round 1
// baseline (414.012 us; speedup 1.0000x reference)
//
#include <hip/hip_runtime.h>
#include <math.h>

#define N_NODES 5000
#define N_EDGES 50000
#define D 64

// ---------------- zero the aggregation buffer (ws is poisoned 0xAA) --------
__global__ void zero_kernel(float* __restrict__ p, int n) {
    int i = blockIdx.x * 256 + threadIdx.x;
    if (i < n) p[i] = 0.f;
}

// ---------------- t = relu(ef @ W1 + b1)  (E, 64) --------------------------
__global__ void edge_mlp1_kernel(const float* __restrict__ ef,
                                 const float* __restrict__ W1,
                                 const float* __restrict__ b1,
                                 float* __restrict__ t) {
    int gid = blockIdx.x * 256 + threadIdx.x;   // grid exact: 12500*256 = E*64
    int e = gid >> 6, i = gid & 63;
    float acc = b1[i];
#pragma unroll
    for (int k = 0; k < 16; ++k)
        acc += ef[e * 16 + k] * W1[k * 64 + i];
    t[gid] = fmaxf(acc, 0.f);
}

// ---------------- V[n][i][k] = sum_j h[n,j] * W2[k, i*64+j] ----------------
// Tiled GEMM: block = (i0, node-tile of 64). W2flat[(k*64+i0)*64 + j] rows.
__global__ __launch_bounds__(256) void vmat_kernel(const float* __restrict__ h,
                                                   const float* __restrict__ W2,
                                                   float* __restrict__ V) {
    __shared__ float hs[64 * 65];   // [j][node]   (+1 pad: conflict-free)
    __shared__ float ws[64 * 65];   // [j][k]
    int tid = threadIdx.x;
    int i0 = blockIdx.x;            // 0..63 : output-row index i
    int m0 = blockIdx.y * 64;       // node tile base
#pragma unroll
    for (int it = 0; it < 16; ++it) {
        int idx = it * 256 + tid;
        int row = idx >> 6, col = idx & 63;   // row = node-in-tile / k ; col = j
        int n = m0 + row;
        hs[col * 65 + row] = (n < N_NODES) ? h[n * 64 + col] : 0.f;
        // W2 row (row*64 + i0): address row*4096 + i0*64 + col  (coalesced in col)
        ws[col * 65 + row] = W2[row * 4096 + i0 * 64 + col];
    }
    __syncthreads();
    int ty = tid >> 4, tx = tid & 15;
    float acc[4][4] = {};
    for (int j = 0; j < 64; ++j) {
        float hv[4], wv[4];
#pragma unroll
        for (int a = 0; a < 4; ++a) hv[a] = hs[j * 65 + ty * 4 + a];
#pragma unroll
        for (int b = 0; b < 4; ++b) wv[b] = ws[j * 65 + tx * 4 + b];
#pragma unroll
        for (int a = 0; a < 4; ++a)
#pragma unroll
            for (int b = 0; b < 4; ++b)
                acc[a][b] += hv[a] * wv[b];
    }
#pragma unroll
    for (int a = 0; a < 4; ++a) {
        int n = m0 + ty * 4 + a;
        if (n < N_NODES) {
            float4 o = make_float4(acc[a][0], acc[a][1], acc[a][2], acc[a][3]);
            ((float4*)V)[n * 1024 + i0 * 16 + tx] = o;   // V[n][i0][tx*4..+3]
        }
    }
}

// ---------------- Wb[n][i] = sum_j h[n,j] * b2[i*64+j] ---------------------
__global__ void wb_kernel(const float* __restrict__ h,
                          const float* __restrict__ b2,
                          float* __restrict__ Wb) {
    int gid = blockIdx.x * 256 + threadIdx.x;   // exact: 1250*256 = N*64
    int n = gid >> 6, i = gid & 63;
    const float4* h4 = (const float4*)(h + n * 64);
    const float4* b24 = (const float4*)(b2 + i * 64);
    float acc = 0.f;
#pragma unroll
    for (int jb = 0; jb < 16; ++jb) {
        float4 hv = h4[jb], bv = b24[jb];
        acc += hv.x * bv.x + hv.y * bv.y + hv.z * bv.z + hv.w * bv.w;
    }
    Wb[gid] = acc;
}

// ---------------- msg[e,i] = sum_k t[e,k] V[src][i][k] + Wb[src][i] --------
// one wave per edge; lane = output index i; atomic scatter into m[tgt]
__global__ void msg_kernel(const int* __restrict__ ei,
                           const float* __restrict__ t,
                           const float* __restrict__ V,
                           const float* __restrict__ Wb,
                           float* __restrict__ m) {
    int wave = threadIdx.x >> 6;
    int lane = threadIdx.x & 63;
    int e = blockIdx.x * 4 + wave;              // exact: 12500*4 = E
    int src = ei[e];
    int tgt = ei[N_EDGES + e];
    float tval = t[e * 64 + lane];              // lane holds t[e,lane]
    const float4* V4 = (const float4*)V + (size_t)src * 1024 + lane * 16;
    float acc = Wb[src * 64 + lane];
#pragma unroll
    for (int kb = 0; kb < 16; ++kb) {
        float4 v = V4[kb];
        float t0 = __shfl(tval, kb * 4 + 0);
        float t1 = __shfl(tval, kb * 4 + 1);
        float t2 = __shfl(tval, kb * 4 + 2);
        float t3 = __shfl(tval, kb * 4 + 3);
        acc += t0 * v.x + t1 * v.y + t2 * v.z + t3 * v.w;
    }
    atomicAdd(&m[tgt * 64 + lane], acc);
}

// ---------------- GRU cell: h_new = GRU(m, h) ------------------------------
__global__ void gru_kernel(const float* __restrict__ m,
                           const float* __restrict__ h,
                           const float* __restrict__ Wih,
                           const float* __restrict__ Whh,
                           const float* __restrict__ bih,
                           const float* __restrict__ bhh,
                           float* __restrict__ out) {
    __shared__ float sm[4][64];
    __shared__ float sh[4][64];
    int w = threadIdx.x >> 6, lane = threadIdx.x & 63;
    int n = blockIdx.x * 4 + w;                 // exact: 1250*4 = N
    sm[w][lane] = m[n * 64 + lane];
    sh[w][lane] = h[n * 64 + lane];
    __syncthreads();
    int i = lane;
    float ir = bih[i], iz = bih[64 + i], inn = bih[128 + i];
    float hr = bhh[i], hz = bhh[64 + i], hn = bhh[128 + i];
    const float4* wri = (const float4*)(Wih + i * 64);
    const float4* wzi = (const float4*)(Wih + (64 + i) * 64);
    const float4* wni = (const float4*)(Wih + (128 + i) * 64);
    const float4* wrh = (const float4*)(Whh + i * 64);
    const float4* wzh = (const float4*)(Whh + (64 + i) * 64);
    const float4* wnh = (const float4*)(Whh + (128 + i) * 64);
    const float4* mv4 = (const float4*)sm[w];
    const float4* hv4 = (const float4*)sh[w];
#pragma unroll
    for (int jb = 0; jb < 16; ++jb) {
        float4 mv = mv4[jb], hv = hv4[jb];
        float4 a;
        a = wri[jb]; ir  += mv.x * a.x + mv.y * a.y + mv.z * a.z + mv.w * a.w;
        a = wzi[jb]; iz  += mv.x * a.x + mv.y * a.y + mv.z * a.z + mv.w * a.w;
        a = wni[jb]; inn += mv.x * a.x + mv.y * a.y + mv.z * a.z + mv.w * a.w;
        a = wrh[jb]; hr  += hv.x * a.x + hv.y * a.y + hv.z * a.z + hv.w * a.w;
        a = wzh[jb]; hz  += hv.x * a.x + hv.y * a.y + hv.z * a.z + hv.w * a.w;
        a = wnh[jb]; hn  += hv.x * a.x + hv.y * a.y + hv.z * a.z + hv.w * a.w;
    }
    float r = 1.f / (1.f + expf(-(ir + hr)));
    float z = 1.f / (1.f + expf(-(iz + hz)));
    float nn = tanhf(inn + r * hn);
    out[n * 64 + i] = (1.f - z) * nn + z * sh[w][i];
}

extern "C" void kernel_launch(void* const* d_in, const int* in_sizes, int n_in,
                              void* d_out, int out_size, void* d_ws, size_t ws_size,
                              hipStream_t stream) {
    const float* h   = (const float*)d_in[0];
    const int*   ei  = (const int*)d_in[1];    // [2, E]: row0 = src, row1 = tgt
    const float* ef  = (const float*)d_in[2];
    const float* W1  = (const float*)d_in[3];
    const float* b1  = (const float*)d_in[4];
    const float* W2  = (const float*)d_in[5];
    const float* b2  = (const float*)d_in[6];
    const float* Wih = (const float*)d_in[7];
    const float* Whh = (const float*)d_in[8];
    const float* bih = (const float*)d_in[9];
    const float* bhh = (const float*)d_in[10];
    float* out = (float*)d_out;

    // workspace layout (fp32): t | V | Wb | m   = ~97.3 MB
    float* t  = (float*)d_ws;                          // E*64
    float* V  = t  + (size_t)N_EDGES * 64;             // N*4096
    float* Wb = V  + (size_t)N_NODES * 4096;           // N*64
    float* m  = Wb + (size_t)N_NODES * 64;             // N*64

    zero_kernel<<<1250, 256, 0, stream>>>(m, N_NODES * 64);
    edge_mlp1_kernel<<<12500, 256, 0, stream>>>(ef, W1, b1, t);
    vmat_kernel<<<dim3(64, 79), 256, 0, stream>>>(h, W2, V);
    wb_kernel<<<1250, 256, 0, stream>>>(h, b2, Wb);
    msg_kernel<<<12500, 256, 0, stream>>>(ei, t, V, Wb, m);
    gru_kernel<<<1250, 256, 0, stream>>>(m, h, Wih, Whh, bih, bhh, out);
}

// Round 2
// 254.221 us; speedup vs baseline: 1.6286x; 1.6286x over previous
//
#include <hip/hip_runtime.h>
#include <math.h>

#define N_NODES 5000
#define N_EDGES 50000

// ---------------- zero m (as bits) + cnt in one pass -----------------------
__global__ void zero_kernel(int* __restrict__ p, int n) {
    int i = blockIdx.x * 256 + threadIdx.x;
    if (i < n) p[i] = 0;
}

// ---------------- t = relu(ef @ W1 + b1)  (E, 64) --------------------------
__global__ void edge_mlp1_kernel(const float* __restrict__ ef,
                                 const float* __restrict__ W1,
                                 const float* __restrict__ b1,
                                 float* __restrict__ t) {
    int gid = blockIdx.x * 256 + threadIdx.x;   // grid exact: 12500*256 = E*64
    int e = gid >> 6, i = gid & 63;             // e is wave-uniform -> s_loads
    float acc = b1[i];
#pragma unroll
    for (int k = 0; k < 16; ++k)
        acc += ef[e * 16 + k] * W1[k * 64 + i];
    t[gid] = fmaxf(acc, 0.f);
}

// ---------------- V[n][k][i] = sum_j h[n,j] * W2[k, i*64+j] ----------------
// block = (k0, node-tile of 64). W2 chunk for k0 is one contiguous 16 KB row.
__global__ __launch_bounds__(256) void vmat_kernel(const float* __restrict__ h,
                                                   const float* __restrict__ W2,
                                                   float* __restrict__ V) {
    __shared__ float hs[64 * 65];   // [j][node]
    __shared__ float wsT[64 * 65];  // [j][i]
    int tid = threadIdx.x;
    int k0 = blockIdx.x;            // 0..63
    int m0 = blockIdx.y * 64;       // node tile base
#pragma unroll
    for (int it = 0; it < 16; ++it) {
        int idx = it * 256 + tid;
        int row = idx >> 6, col = idx & 63;       // (node-in-tile, j) / (i, j)
        int n = m0 + row;
        hs[col * 65 + row] = (n < N_NODES) ? h[n * 64 + col] : 0.f;
        wsT[col * 65 + row] = W2[k0 * 4096 + idx];   // wsT[j][i] = W2[k0, row*64+col]
    }
    __syncthreads();
    int ty = tid >> 4, tx = tid & 15;
    float acc[4][4] = {};
#pragma unroll 4
    for (int j = 0; j < 64; ++j) {
        float hv[4], wv[4];
#pragma unroll
        for (int a = 0; a < 4; ++a) hv[a] = hs[j * 65 + ty * 4 + a];
#pragma unroll
        for (int b = 0; b < 4; ++b) wv[b] = wsT[j * 65 + tx * 4 + b];
#pragma unroll
        for (int a = 0; a < 4; ++a)
#pragma unroll
            for (int b = 0; b < 4; ++b)
                acc[a][b] += hv[a] * wv[b];
    }
#pragma unroll
    for (int a = 0; a < 4; ++a) {
        int n = m0 + ty * 4 + a;
        if (n < N_NODES) {
            float4 o = make_float4(acc[a][0], acc[a][1], acc[a][2], acc[a][3]);
            ((float4*)V)[(size_t)n * 1024 + k0 * 16 + tx] = o;  // V[n][k0][tx*4..+3]
        }
    }
}

// ---------------- Wb[n][i] = sum_j h[n,j] * b2[i*64+j] ---------------------
__global__ void wb_kernel(const float* __restrict__ h,
                          const float* __restrict__ b2,
                          float* __restrict__ Wb) {
    int gid = blockIdx.x * 256 + threadIdx.x;   // exact: 1250*256 = N*64
    int n = gid >> 6, i = gid & 63;
    const float4* h4 = (const float4*)(h + n * 64);
    const float4* b24 = (const float4*)(b2 + i * 64);
    float acc = 0.f;
#pragma unroll
    for (int jb = 0; jb < 16; ++jb) {
        float4 hv = h4[jb], bv = b24[jb];
        acc += hv.x * bv.x + hv.y * bv.y + hv.z * bv.z + hv.w * bv.w;
    }
    Wb[gid] = acc;
}

// ---------------- counting sort of edges by src ----------------------------
__global__ void hist_kernel(const int* __restrict__ ei, int* __restrict__ cnt) {
    int e = blockIdx.x * 256 + threadIdx.x;
    if (e < N_EDGES) atomicAdd(&cnt[ei[e]], 1);
}

__global__ __launch_bounds__(1024) void scan_kernel(const int* __restrict__ cnt,
                                                    int* __restrict__ off,
                                                    int* __restrict__ cur) {
    __shared__ int s[1024];
    int tid = threadIdx.x;
    int base = tid * 5;                           // 1024*5 = 5120 >= 5000
    int loc[5]; int sum = 0;
#pragma unroll
    for (int q = 0; q < 5; ++q) {
        int v = (base + q < N_NODES) ? cnt[base + q] : 0;
        loc[q] = sum; sum += v;
    }
    s[tid] = sum; __syncthreads();
    for (int d = 1; d < 1024; d <<= 1) {
        int v = (tid >= d) ? s[tid - d] : 0;
        __syncthreads();
        s[tid] += v;
        __syncthreads();
    }
    int excl = (tid > 0) ? s[tid - 1] : 0;
#pragma unroll
    for (int q = 0; q < 5; ++q)
        if (base + q < N_NODES) { off[base + q] = excl + loc[q]; cur[base + q] = excl + loc[q]; }
    if (tid == 1023) off[N_NODES] = excl + sum;
}

__global__ void scatter_kernel(const int* __restrict__ ei,
                               int* __restrict__ cur, int* __restrict__ eperm) {
    int e = blockIdx.x * 256 + threadIdx.x;
    if (e < N_EDGES) {
        int p = atomicAdd(&cur[ei[e]], 1);
        eperm[p] = e;
    }
}

// ---------------- per-src messages: V[src] lives in 64 VGPRs ---------------
// wave w handles node n = blockIdx*4+w; processes all edges with src==n.
__global__ __launch_bounds__(256) void msg_kernel(const int* __restrict__ ei,
                                                  const int* __restrict__ off,
                                                  const int* __restrict__ eperm,
                                                  const float* __restrict__ t,
                                                  const float* __restrict__ V,
                                                  const float* __restrict__ Wb,
                                                  float* __restrict__ m) {
    int wave = threadIdx.x >> 6;
    int lane = threadIdx.x & 63;
    int n = blockIdx.x * 4 + wave;                // exact: 1250*4 = N
    int s0 = off[n], s1 = off[n + 1];
    if (s0 == s1) return;
    const float* Vn = V + (size_t)n * 4096;
    float vreg[64];
#pragma unroll
    for (int k = 0; k < 64; ++k) vreg[k] = Vn[k * 64 + lane];   // coalesced
    float wb = Wb[n * 64 + lane];
    for (int p = s0; p < s1; ++p) {
        int e = eperm[p];
        int tgt = ei[N_EDGES + e];
        float tval = t[e * 64 + lane];
        float acc = wb;
#pragma unroll
        for (int k = 0; k < 64; ++k)
            acc += __shfl(tval, k) * vreg[k];
        atomicAdd(&m[tgt * 64 + lane], acc);
    }
}

// ---------------- transpose GRU weights: WT[j][row] ------------------------
__global__ void transpose_w_kernel(const float* __restrict__ Wih,
                                   const float* __restrict__ Whh,
                                   float* __restrict__ WihT,
                                   float* __restrict__ WhhT) {
    int idx = blockIdx.x * 256 + threadIdx.x;     // exact: 96*256 = 2*192*64
    int which = idx >= 12288;
    int tt = which ? idx - 12288 : idx;
    int row = tt >> 6, j = tt & 63;
    const float* src = which ? Whh : Wih;
    float* dst = which ? WhhT : WihT;
    dst[j * 192 + row] = src[tt];
}

// ---------------- GRU cell with coalesced (transposed) weights -------------
__global__ void gru_kernel(const float* __restrict__ m,
                           const float* __restrict__ h,
                           const float* __restrict__ WihT,
                           const float* __restrict__ WhhT,
                           const float* __restrict__ bih,
                           const float* __restrict__ bhh,
                           float* __restrict__ out) {
    __shared__ float sm[4][64];
    __shared__ float sh[4][64];
    int w = threadIdx.x >> 6, lane = threadIdx.x & 63;
    int n = blockIdx.x * 4 + w;                   // exact: 1250*4 = N
    sm[w][lane] = m[n * 64 + lane];
    sh[w][lane] = h[n * 64 + lane];
    __syncthreads();
    int i = lane;
    float ir = bih[i], iz = bih[64 + i], inn = bih[128 + i];
    float hr = bhh[i], hz = bhh[64 + i], hn = bhh[128 + i];
#pragma unroll 4
    for (int j = 0; j < 64; ++j) {
        float mv = sm[w][j];                      // LDS broadcast (free)
        float hv = sh[w][j];
        const float* wi = WihT + j * 192;         // lane-coalesced 256B rows
        const float* wh = WhhT + j * 192;
        ir  += mv * wi[i];
        iz  += mv * wi[64 + i];
        inn += mv * wi[128 + i];
        hr  += hv * wh[i];
        hz  += hv * wh[64 + i];
        hn  += hv * wh[128 + i];
    }
    float r = 1.f / (1.f + expf(-(ir + hr)));
    float z = 1.f / (1.f + expf(-(iz + hz)));
    float nn = tanhf(inn + r * hn);
    out[n * 64 + i] = (1.f - z) * nn + z * sh[w][i];
}

extern "C" void kernel_launch(void* const* d_in, const int* in_sizes, int n_in,
                              void* d_out, int out_size, void* d_ws, size_t ws_size,
                              hipStream_t stream) {
    const float* h   = (const float*)d_in[0];
    const int*   ei  = (const int*)d_in[1];    // [2, E]: row0 = src, row1 = tgt
    const float* ef  = (const float*)d_in[2];
    const float* W1  = (const float*)d_in[3];
    const float* b1  = (const float*)d_in[4];
    const float* W2  = (const float*)d_in[5];
    const float* b2  = (const float*)d_in[6];
    const float* Wih = (const float*)d_in[7];
    const float* Whh = (const float*)d_in[8];
    const float* bih = (const float*)d_in[9];
    const float* bhh = (const float*)d_in[10];
    float* out = (float*)d_out;

    // workspace layout (all 16B-aligned offsets):
    float* t    = (float*)d_ws;                        // E*64
    float* V    = t  + (size_t)N_EDGES * 64;           // N*4096
    float* Wb   = V  + (size_t)N_NODES * 4096;         // N*64
    float* m    = Wb + (size_t)N_NODES * 64;           // N*64
    int*   cnt  = (int*)(m + (size_t)N_NODES * 64);    // N   (adjacent to m!)
    int*   off  = cnt + N_NODES;                       // N+1
    int*   cur  = off + N_NODES + 1;                   // N
    int*   eperm= cur + N_NODES;                       // E
    float* WihT = (float*)(eperm + N_EDGES);           // 192*64
    float* WhhT = WihT + 192 * 64;                     // 192*64

    // zero m (N*64 floats) and cnt (N ints) together — they are adjacent
    zero_kernel<<<(N_NODES * 64 + N_NODES + 255) / 256, 256, 0, stream>>>(
        (int*)m, N_NODES * 64 + N_NODES);
    edge_mlp1_kernel<<<12500, 256, 0, stream>>>(ef, W1, b1, t);
    vmat_kernel<<<dim3(64, 79), 256, 0, stream>>>(h, W2, V);
    wb_kernel<<<1250, 256, 0, stream>>>(h, b2, Wb);
    hist_kernel<<<(N_EDGES + 255) / 256, 256, 0, stream>>>(ei, cnt);
    scan_kernel<<<1, 1024, 0, stream>>>(cnt, off, cur);
    scatter_kernel<<<(N_EDGES + 255) / 256, 256, 0, stream>>>(ei, cur, eperm);
    msg_kernel<<<1250, 256, 0, stream>>>(ei, off, eperm, t, V, Wb, m);
    transpose_w_kernel<<<96, 256, 0, stream>>>(Wih, Whh, WihT, WhhT);
    gru_kernel<<<1250, 256, 0, stream>>>(m, h, WihT, WhhT, bih, bhh, out);
}